// Round 1
// 771.908 us; speedup vs baseline: 1.0098x; 1.0098x over previous
//
#include <hip/hip_runtime.h>
#include <math.h>

#define Tc 2048
#define Dc 1024
#define Hc 16
#define HDc 64
#define BT 4096                     // B*T
#define SCALE 0.35355339059327379f  // 64^-0.25

typedef _Float16 f16;
typedef __attribute__((ext_vector_type(4))) _Float16 f16x4;
typedef __attribute__((ext_vector_type(8))) _Float16 f16x8;
typedef __attribute__((ext_vector_type(4))) float f32x4;

__device__ __forceinline__ void gload16(const f16* g, f16* l)
{
    __builtin_amdgcn_global_load_lds(
        (const __attribute__((address_space(1))) void*)g,
        (__attribute__((address_space(3))) void*)l, 16, 0, 0);
}

// ---------------------------------------------------------------------------
// fused casts: 8 units of 1M floats (x in 4 chunks + 4 weights)
// ---------------------------------------------------------------------------
__global__ __launch_bounds__(256)
void cast_kernel(const float* __restrict__ x,
                 const float* __restrict__ Wq, const float* __restrict__ Wk,
                 const float* __restrict__ Wv, const float* __restrict__ Wo,
                 f16* __restrict__ xh,
                 f16* __restrict__ Wqh, f16* __restrict__ Wkh,
                 f16* __restrict__ Wvh, f16* __restrict__ Woh)
{
    const int u = blockIdx.y;
    const float* s; f16* d;
    if (u < 4) { s = x + (size_t)u * (1u << 20); d = xh + (size_t)u * (1u << 20); }
    else switch (u) {
        case 4:  s = Wq; d = Wqh; break;
        case 5:  s = Wk; d = Wkh; break;
        case 6:  s = Wv; d = Wvh; break;
        default: s = Wo; d = Woh; break;
    }
    int i = blockIdx.x * 256 + threadIdx.x;
    float4 v = ((const float4*)s)[i];
    f16x4 o = {(f16)v.x, (f16)v.y, (f16)v.z, (f16)v.w};
    ((f16x4*)d)[i] = o;
}

// ---------------------------------------------------------------------------
// m97-style GEMM core: 128x128 tile, BK=64, global_load_lds(16B) staging,
// T2 XOR swizzle (linear LDS dest, pre-swizzled global source, swizzled read).
// C(BT x Dc) = A * W^T.   Swizzle involution: byte-in-row ^= ((row&7)<<4).
// ---------------------------------------------------------------------------
#define GEMM_BODY(Aptr, Bptr)                                                        \
    __shared__ f16 As[128][64];                                                      \
    __shared__ f16 Bs[128][64];                                                      \
    const int tid = threadIdx.x;                                                     \
    const int w = tid >> 6, l = tid & 63;                                            \
    const int lr = l & 15, lq = l >> 4;                                              \
    const int wr = w >> 1, wc = w & 1;                                               \
    const int m0 = blockIdx.y * 128, n0 = blockIdx.x * 128;                          \
    const int srow8 = l >> 3, sslot = l & 7;                                         \
    f32x4 acc[4][4] = {};                                                            \
    for (int k0 = 0; k0 < Dc; k0 += 64) {                                            \
        __syncthreads();                                                             \
        _Pragma("unroll")                                                            \
        for (int c = 0; c < 4; c++) {                                                \
            int chunk = w * 4 + c;                                                   \
            int row = chunk * 8 + srow8;                                             \
            int col = (sslot ^ (row & 7)) * 8;                                       \
            gload16(&Aptr[(size_t)(m0 + row) * Dc + k0 + col],                       \
                    (f16*)((char*)&As[0][0] + chunk * 1024));                        \
            gload16(&Bptr[(size_t)(n0 + row) * Dc + k0 + col],                       \
                    (f16*)((char*)&Bs[0][0] + chunk * 1024));                        \
        }                                                                            \
        __syncthreads();                                                             \
        _Pragma("unroll")                                                            \
        for (int kk = 0; kk < 2; kk++) {                                             \
            f16x8 af[4], bf[4];                                                      \
            _Pragma("unroll")                                                        \
            for (int mi = 0; mi < 4; mi++) {                                         \
                int row = 64 * wr + 16 * mi + lr;                                    \
                int bo = (lq * 16 + kk * 64) ^ ((row & 7) << 4);                     \
                af[mi] = *(const f16x8*)((const char*)&As[0][0] + row * 128 + bo);   \
            }                                                                        \
            _Pragma("unroll")                                                        \
            for (int ni = 0; ni < 4; ni++) {                                         \
                int row = 64 * wc + 16 * ni + lr;                                    \
                int bo = (lq * 16 + kk * 64) ^ ((row & 7) << 4);                     \
                bf[ni] = *(const f16x8*)((const char*)&Bs[0][0] + row * 128 + bo);   \
            }                                                                        \
            _Pragma("unroll")                                                        \
            for (int mi = 0; mi < 4; mi++)                                           \
                _Pragma("unroll")                                                    \
                for (int ni = 0; ni < 4; ni++)                                       \
                    acc[mi][ni] = __builtin_amdgcn_mfma_f32_16x16x32_f16(            \
                        af[mi], bf[ni], acc[mi][ni], 0, 0, 0);                       \
        }                                                                            \
    }

// fused QKV projection + RoPE/scale epilogue, store f16 (B,H,T,HD)
__global__ __launch_bounds__(256)
void qkv_proj_kernel(const f16* __restrict__ xh,
                     const f16* __restrict__ Wqh, const f16* __restrict__ Wkh,
                     const f16* __restrict__ Wvh,
                     const float* __restrict__ bq, const float* __restrict__ bv,
                     f16* __restrict__ qh, f16* __restrict__ kh, f16* __restrict__ vh,
                     const float* __restrict__ cosp, const float* __restrict__ sinp)
{
    const int mode = blockIdx.z;
    const f16* W = (mode == 0) ? Wqh : (mode == 1 ? Wkh : Wvh);
    const float* bias = (mode == 0) ? bq : (mode == 2 ? bv : nullptr);
    f16* dst = (mode == 0) ? qh : (mode == 1 ? kh : vh);

    GEMM_BODY(xh, W)

    #pragma unroll
    for (int mi = 0; mi < 4; mi++) {
        #pragma unroll
        for (int ni = 0; ni < 4; ni++) {
            #pragma unroll
            for (int i = 0; i < 4; i++) {
                int gm = m0 + 64 * wr + 16 * mi + lq * 4 + i;
                int gn = n0 + 64 * wc + 16 * ni + lr;
                float v = acc[mi][ni][i];
                if (bias) v += bias[gn];
                int b = gm >> 11, t = gm & 2047;
                int h = gn >> 6, d = gn & 63;
                if (mode != 2) {
                    float pv = __shfl_xor(v, 1, 64);   // partner col gn^1
                    int p = d >> 1;
                    float c = cosp[t * 32 + p], s = sinp[t * 32 + p];
                    v = (d & 1) ? (pv * s + v * c) : (v * c - pv * s);
                    v *= SCALE;
                }
                dst[((size_t)(b * Hc + h) * Tc + t) * HDc + d] = (f16)v;
            }
        }
    }
}

// out projection: out(BT x Dc) = wvh * Wo^T + bo, fp32 store
__global__ __launch_bounds__(256)
void out_proj_kernel(const f16* __restrict__ A, const f16* __restrict__ W,
                     const float* __restrict__ bias, float* __restrict__ out)
{
    GEMM_BODY(A, W)

    #pragma unroll
    for (int mi = 0; mi < 4; mi++)
        #pragma unroll
        for (int ni = 0; ni < 4; ni++)
            #pragma unroll
            for (int i = 0; i < 4; i++) {
                int gm = m0 + 64 * wr + 16 * mi + lq * 4 + i;
                int gn = n0 + 64 * wc + 16 * ni + lr;
                out[(size_t)gm * Dc + gn] = acc[mi][ni][i] + bias[gn];
            }
}

// ---------------------------------------------------------------------------
// flash attention + S writeback, with T14 async-STAGE split:
// K/V tile for iteration i+1 is global-loaded into registers during the
// compute phase of iteration i; ds_write lands after the next barrier.
// Raw s_barrier + explicit lgkmcnt(0) (NOT __syncthreads — that drains
// vmcnt(0) and would serialize the prefetch).
// ---------------------------------------------------------------------------
__global__ __launch_bounds__(256)
void flash_kernel(const f16* __restrict__ qh, const f16* __restrict__ kh,
                  const f16* __restrict__ vh, f16* __restrict__ wvh,
                  float* __restrict__ qk)
{
    const int z = blockIdx.y;
    const int t0 = (gridDim.x - 1 - blockIdx.x) * 64;   // longest flash loops first
    const int tid = threadIdx.x;
    const int w = tid >> 6, l = tid & 63;
    const int lr = l & 15, lq = l >> 4;

    __shared__ f16 Qs[64][72];
    __shared__ f16 Ks[64][72];
    __shared__ f16 VsT[64][72];   // [d][s]
    __shared__ f16 Ps[64][72];    // [m][s]

    const f16* Qg = qh + (size_t)z * Tc * HDc;
    const f16* Kg = kh + (size_t)z * Tc * HDc;
    const f16* Vg = vh + (size_t)z * Tc * HDc;
    float* C = qk + (size_t)z * Tc * Tc;

    {
        int r = tid >> 2, c = (tid & 3) * 16;
        *(f16x8*)&Qs[r][c]     = *(const f16x8*)&Qg[(size_t)(t0 + r) * HDc + c];
        *(f16x8*)&Qs[r][c + 8] = *(const f16x8*)&Qg[(size_t)(t0 + r) * HDc + c + 8];
    }

    // fill strictly-upper portion of this block's 64 rows: cols [t0+64, Tc)
    {
        int r = t0 + (tid >> 2);             // 4 threads per row
        int n4 = (Tc - t0 - 64) >> 2;        // float4s per row (multiple of 16)
        float4 mv; mv.x = mv.y = mv.z = mv.w = -1e9f;
        float4* rowp = (float4*)(C + (size_t)r * Tc + t0 + 64);
        for (int c = (tid & 3); c < n4; c += 4) rowp[c] = mv;
    }

    // preload tile 0 into registers
    const int kr = tid >> 2, kc = (tid & 3) * 16;
    const int vs = tid & 63, vd = (tid >> 6) * 16;
    f16x8 rk0 = *(const f16x8*)&Kg[(size_t)kr * HDc + kc];
    f16x8 rk1 = *(const f16x8*)&Kg[(size_t)kr * HDc + kc + 8];
    f16x8 rv0 = *(const f16x8*)&Vg[(size_t)vs * HDc + vd];
    f16x8 rv1 = *(const f16x8*)&Vg[(size_t)vs * HDc + vd + 8];

    f32x4 O[4] = {};
    float mrow[4], lrow[4];
    #pragma unroll
    for (int i = 0; i < 4; i++) { mrow[i] = -1e30f; lrow[i] = 0.f; }

    for (int s0 = 0; s0 <= t0; s0 += 64) {
        // barrier A: all waves done reading LDS of previous iteration
        asm volatile("" ::: "memory");
        __builtin_amdgcn_s_barrier();
        asm volatile("" ::: "memory");

        // write staged registers to LDS
        *(f16x8*)&Ks[kr][kc]     = rk0;
        *(f16x8*)&Ks[kr][kc + 8] = rk1;
        #pragma unroll
        for (int j = 0; j < 8; j++) {
            VsT[vd + j][vs]     = rv0[j];
            VsT[vd + 8 + j][vs] = rv1[j];
        }

        // prefetch next tile into registers (hidden under this iter's compute)
        if (s0 + 64 <= t0) {
            const f16* kp = &Kg[(size_t)(s0 + 64 + kr) * HDc + kc];
            const f16* vp = &Vg[(size_t)(s0 + 64 + vs) * HDc + vd];
            rk0 = *(const f16x8*)kp;
            rk1 = *(const f16x8*)(kp + 8);
            rv0 = *(const f16x8*)vp;
            rv1 = *(const f16x8*)(vp + 8);
        }

        // barrier B: LDS writes visible (lgkm only — keep prefetch in flight)
        asm volatile("s_waitcnt lgkmcnt(0)" ::: "memory");
        __builtin_amdgcn_s_barrier();
        asm volatile("" ::: "memory");

        // S = Q K^T  (wave strip: q-rows 16w..16w+15, all 64 s)
        f32x4 S[4] = {};
        #pragma unroll
        for (int ks = 0; ks < 2; ks++) {
            f16x8 aq = *(const f16x8*)&Qs[16 * w + lr][lq * 8 + 32 * ks];
            #pragma unroll
            for (int ni = 0; ni < 4; ni++) {
                f16x8 bk = *(const f16x8*)&Ks[16 * ni + lr][lq * 8 + 32 * ks];
                S[ni] = __builtin_amdgcn_mfma_f32_16x16x32_f16(aq, bk, S[ni], 0, 0, 0);
            }
        }

        if (s0 == t0) {   // diagonal tile: causal mask
            #pragma unroll
            for (int ni = 0; ni < 4; ni++)
                #pragma unroll
                for (int i = 0; i < 4; i++) {
                    int tg = t0 + 16 * w + lq * 4 + i;
                    int sg = s0 + 16 * ni + lr;
                    if (sg > tg) S[ni][i] = -1e9f;
                }
        }

        // writeback S tile (output 1), post-mask pre-exp
        #pragma unroll
        for (int ni = 0; ni < 4; ni++)
            #pragma unroll
            for (int i = 0; i < 4; i++) {
                int tg = t0 + 16 * w + lq * 4 + i;
                int sg = s0 + 16 * ni + lr;
                C[(size_t)tg * Tc + sg] = S[ni][i];
            }

        // online softmax per row (rows live across 16 lanes of a quad)
        #pragma unroll
        for (int i = 0; i < 4; i++) {
            float v = fmaxf(fmaxf(S[0][i], S[1][i]), fmaxf(S[2][i], S[3][i]));
            v = fmaxf(v, __shfl_xor(v, 1, 64));
            v = fmaxf(v, __shfl_xor(v, 2, 64));
            v = fmaxf(v, __shfl_xor(v, 4, 64));
            v = fmaxf(v, __shfl_xor(v, 8, 64));
            float mnew = fmaxf(mrow[i], v);
            float alpha = __expf(mrow[i] - mnew);
            mrow[i] = mnew;
            float rs = 0.f;
            #pragma unroll
            for (int ni = 0; ni < 4; ni++) {
                float p = __expf(S[ni][i] - mnew);
                S[ni][i] = p;
                rs += p;
            }
            rs += __shfl_xor(rs, 1, 64);
            rs += __shfl_xor(rs, 2, 64);
            rs += __shfl_xor(rs, 4, 64);
            rs += __shfl_xor(rs, 8, 64);
            lrow[i] = lrow[i] * alpha + rs;
            #pragma unroll
            for (int ni = 0; ni < 4; ni++) O[ni][i] *= alpha;
        }

        // P -> LDS (wave-private strip; no cross-wave hazard)
        #pragma unroll
        for (int ni = 0; ni < 4; ni++)
            #pragma unroll
            for (int i = 0; i < 4; i++)
                Ps[16 * w + lq * 4 + i][16 * ni + lr] = (f16)S[ni][i];

        // O += P V
        #pragma unroll
        for (int ks = 0; ks < 2; ks++) {
            f16x8 ap = *(const f16x8*)&Ps[16 * w + lr][lq * 8 + 32 * ks];
            #pragma unroll
            for (int ni = 0; ni < 4; ni++) {
                f16x8 bv = *(const f16x8*)&VsT[16 * ni + lr][lq * 8 + 32 * ks];
                O[ni] = __builtin_amdgcn_mfma_f32_16x16x32_f16(ap, bv, O[ni], 0, 0, 0);
            }
        }
    }

    const int b = z >> 4, h = z & 15;
    #pragma unroll
    for (int ni = 0; ni < 4; ni++)
        #pragma unroll
        for (int i = 0; i < 4; i++) {
            int tg = t0 + 16 * w + lq * 4 + i;
            int d = 16 * ni + lr;
            float o = O[ni][i] / lrow[i];
            wvh[((size_t)(b * Tc + tg)) * Dc + h * HDc + d] = (f16)o;
        }
}

// ---------------------------------------------------------------------------
extern "C" void kernel_launch(void* const* d_in, const int* in_sizes, int n_in,
                              void* d_out, int out_size, void* d_ws, size_t ws_size,
                              hipStream_t stream)
{
    const float* x    = (const float*)d_in[0];
    const float* cosp = (const float*)d_in[2];
    const float* sinp = (const float*)d_in[3];
    const float* Wq   = (const float*)d_in[4];
    const float* bq   = (const float*)d_in[5];
    const float* Wk   = (const float*)d_in[6];
    const float* Wv   = (const float*)d_in[7];
    const float* bv   = (const float*)d_in[8];
    const float* Wo   = (const float*)d_in[9];
    const float* bo   = (const float*)d_in[10];

    float* out = (float*)d_out;
    float* qk  = out + (size_t)BT * Dc;

    f16* ws  = (f16*)d_ws;
    f16* xh  = ws;
    f16* Wqh = xh  + (size_t)BT * Dc;
    f16* Wkh = Wqh + (size_t)Dc * Dc;
    f16* Wvh = Wkh + (size_t)Dc * Dc;
    f16* Woh = Wvh + (size_t)Dc * Dc;
    f16* qh  = Woh + (size_t)Dc * Dc;
    f16* kh  = qh  + (size_t)BT * Dc;
    f16* vh  = kh  + (size_t)BT * Dc;
    f16* wvh = vh  + (size_t)BT * Dc;

    dim3 blk(256);

    cast_kernel<<<dim3(1024, 8), blk, 0, stream>>>(
        x, Wq, Wk, Wv, Wo, xh, Wqh, Wkh, Wvh, Woh);

    qkv_proj_kernel<<<dim3(Dc / 128, BT / 128, 3), blk, 0, stream>>>(
        xh, Wqh, Wkh, Wvh, bq, bv, qh, kh, vh, cosp, sinp);

    flash_kernel<<<dim3(Tc / 64, 32), blk, 0, stream>>>(qh, kh, vh, wvh, qk);

    out_proj_kernel<<<dim3(Dc / 128, BT / 128), blk, 0, stream>>>(wvh, Woh, bo, out);
}